// Round 3
// baseline (149.837 us; speedup 1.0000x reference)
//
#include <hip/hip_runtime.h>
#include <stdint.h>

// conv_59700045414486: y[b,n,o] = sum_{k,c} x[b, kernel2[n,k], c] * W[k,c,o] + bias[o]
// B=64, N=4096, C=64, OUT=64, K2=4
//
// R8 = R6 structure, defensive resubmit after two container-level failures:
//   - nontemporal stores reverted to plain f32x4 stores (only exotic codegen
//     path vs the R5 kernel that passed; everything else re-audited clean).
//
// R6 rationale: counters showed latency-bound (HBM 33%, MfmaUtil 5.4%,
// Occupancy 9%): 33.8KB LDS capped us at 4 single-wave blocks/CU = 1
// wave/SIMD, so every vmcnt wait was dead SIMD time. Keep the proven
// register-free async-DMA pipeline but halve tile granularity and block size:
//   - half-tiles: 2 of 4 taps per tile = 8KB (16 cols x 2 taps x 64c x 4B),
//     double-buffered 2x8KB; two half-tiles accumulate into acc per phase.
//   - blocks cover 32 sites x 4 batches (8 phases); grid 2048 -> 8 blocks/CU
//     co-resident (LDS 16.9KB/block), 2 waves/SIMD: one wave's vmcnt stall
//     overlaps another's gather-issue/compute.
//   - vmcnt queue exact: 8 loads/half-tile + 4 stores/phase; steady-state
//     wait = vmcnt(12).

#define N_SITES  4096
#define C_DIM    64
#define OUT_DIM  64

typedef __attribute__((ext_vector_type(8))) short bf16x8;
typedef __attribute__((ext_vector_type(4))) float f32x4;

__device__ __forceinline__ uint32_t pack2_bf16(float f0, float f1) {
    uint32_t u0 = __float_as_uint(f0) + 0x8000u;
    uint32_t u1 = __float_as_uint(f1) + 0x8000u;
    return __builtin_amdgcn_perm(u1, u0, 0x07060302u);  // [bf16(f1)|bf16(f0)]
}

template<int N> __device__ __forceinline__ void wait_vmcnt() {
    asm volatile("s_waitcnt vmcnt(%0)" :: "n"(N) : "memory");
}

// async 16B/lane global->LDS DMA; LDS dst = M0 + lane*16 (wave-uniform M0)
__device__ __forceinline__ void gll16(const float* p, uint32_t m0v) {
    asm volatile("s_mov_b32 m0, %1\n\t"
                 "global_load_lds_dwordx4 %0, off"
                 :: "v"(p), "s"(m0v) : "memory");
}

__global__ __launch_bounds__(64, 1)
void conv_async_kernel(const float* __restrict__ x, const float* __restrict__ W,
                       const float* __restrict__ bias, const int* __restrict__ kernel2,
                       float* __restrict__ out)
{
    // [0,16384): two 8KB half-tile slots; [16384,16896): 32 sites' idx (int4)
    __shared__ __align__(16) uint8_t lds_raw[16896];

    const int lane = threadIdx.x;          // 64 threads = 1 wave
    const int bi   = blockIdx.x;
    const int sg   = bi >> 4;              // 128 site-groups of 32 sites
    const int bg   = bi & 15;              // 16 batch-groups of 4 (bi%8 ~ XCD)
    const int n0   = sg * 32;
    const int b0   = bg * 4;

    const int c  = lane & 15;              // MFMA col = (site sl, batch bb)
    const int q  = lane >> 4;              // k-quad; D row (o) = q*4+reg
    const int sl = c >> 2;
    const int bb = c & 3;

    // ---- stage this block's kernel2 slice into LDS (in-loop idx reads are
    //      ds_read/lgkmcnt, keeping the vmcnt queue = tiles+stores only)
    if (lane < 32) {
        int4 iv = ((const int4*)kernel2)[n0 + lane];
        *(int4*)(lds_raw + 16384 + lane * 16) = iv;
    }

    // ---- A-fragments of W in registers, for the whole kernel (128 VGPRs)
    // A[m=c][k=q*8+j] for o = t*16+c, kk-block s: aw[t][s]; s = tap*2 + hs
    bf16x8 aw[4][8];
    #pragma unroll
    for (int t = 0; t < 4; ++t)
        #pragma unroll
        for (int s = 0; s < 8; ++s) {
            uint32_t* ap = (uint32_t*)&aw[t][s];
            #pragma unroll
            for (int u = 0; u < 4; ++u) {
                float f0 = W[(size_t)(s*32 + q*8 + 2*u    ) * OUT_DIM + t*16 + c];
                float f1 = W[(size_t)(s*32 + q*8 + 2*u + 1) * OUT_DIM + t*16 + c];
                ap[u] = pack2_bf16(f0, f1);
            }
        }

    f32x4 bias_r[4];
    #pragma unroll
    for (int t = 0; t < 4; ++t) bias_r[t] = *(const f32x4*)&bias[t*16 + q*4];

    // per-lane gather base: batch plane + this lane's 16B piece (pcq = q)
    const float* gx = x + (size_t)(b0 + bb) * (N_SITES * C_DIM) + q * 4;

    // LDS byte offset of lds_raw for M0 (flat shared ptr low bits = offset)
    const uint32_t lds0 =
        __builtin_amdgcn_readfirstlane((uint32_t)(uintptr_t)lds_raw);

    // drain prologue loads: vmcnt queue must start empty for exact counting
    wait_vmcnt<0>();

    // half-tile i: phase pp=i>>1, taps {2h, 2h+1} with h=i&1, LDS slot i&1.
    // slot layout: instr j2 = kl*4+hs*2+j at slot*8192 + j2*1024; lane(q,c)
    // within instr block at q*256 + c*16. readback for s_local=kl*2+hs:
    // b128 at slot*8192 + s_local*2048 + q*512 + c*16 (+256).
    auto issue_ht = [&](int i) {
        const uint8_t* ib = lds_raw + 16384 + (i >> 1) * 64 + (i & 1) * 8;
        int2 iv0 = *(const int2*)(ib);        // sites sl=0..3, taps {2h,2h+1}
        int2 iv1 = *(const int2*)(ib + 16);
        int2 iv2 = *(const int2*)(ib + 32);
        int2 iv3 = *(const int2*)(ib + 48);
        const uint32_t m0b = lds0 + (uint32_t)(i & 1) * 8192;
        #pragma unroll
        for (int kl = 0; kl < 2; ++kl) {
            const int e0 = kl ? iv0.y : iv0.x;
            const int e1 = kl ? iv1.y : iv1.x;
            const int e2 = kl ? iv2.y : iv2.x;
            const int e3 = kl ? iv3.y : iv3.x;
            const int nk = (sl & 2) ? ((sl & 1) ? e3 : e2)
                                    : ((sl & 1) ? e1 : e0);
            const float* row = gx + (size_t)(uint32_t)nk * C_DIM;
            gll16(row,      m0b + (uint32_t)(kl*4 + 0) * 1024);  // hs0 j0
            gll16(row + 16, m0b + (uint32_t)(kl*4 + 1) * 1024);  // hs0 j1
            gll16(row + 32, m0b + (uint32_t)(kl*4 + 2) * 1024);  // hs1 j0
            gll16(row + 48, m0b + (uint32_t)(kl*4 + 3) * 1024);  // hs1 j1
        }
    };

    // compute half-tile i (4 K=32 blocks), accumulate; aw s-index = 4h+s_local
    auto comp_ht = [&](int i, f32x4* acc) {
        const uint32_t tb = (uint32_t)(i & 1) * 8192;
        const int hb = (i & 1) * 4;
        #pragma unroll
        for (int s = 0; s < 4; ++s) {
            const uint8_t* pb = lds_raw + tb + s*2048 + q*512 + c*16;
            f32x4 xa = *(const f32x4*)(pb);        // kk-local q*8+0..3
            f32x4 xb = *(const f32x4*)(pb + 256);  // kk-local q*8+4..7
            bf16x8 bf;
            uint32_t* bp = (uint32_t*)&bf;
            bp[0] = pack2_bf16(xa[0], xa[1]);
            bp[1] = pack2_bf16(xa[2], xa[3]);
            bp[2] = pack2_bf16(xb[0], xb[1]);
            bp[3] = pack2_bf16(xb[2], xb[3]);
            #pragma unroll
            for (int t = 0; t < 4; ++t)
                acc[t] = __builtin_amdgcn_mfma_f32_16x16x32_bf16(aw[t][hb + s], bf, acc[t], 0, 0, 0);
        }
    };

    issue_ht(0);
    issue_ht(1);

    // 8 phases x 2 half-tiles. vmcnt accounting (younger-than-target):
    //  subA p=0: HT1 = 8;  subA p>=1: HT(2p+1) + S(p-1) = 12
    //  subB p=0: HT2 = 8;  subB 1<=p<=6: S(p-1) + HT(2p+2) = 12; p=7: S6 = 4
    #pragma unroll
    for (int p = 0; p < 8; ++p) {
        f32x4 acc[4];
        #pragma unroll
        for (int t = 0; t < 4; ++t) acc[t] = (f32x4){0.f, 0.f, 0.f, 0.f};

        if (p == 0) wait_vmcnt<8>();
        else        wait_vmcnt<12>();
        comp_ht(2*p, acc);
        if (p < 7) issue_ht(2*p + 2);

        if      (p == 0) wait_vmcnt<8>();
        else if (p == 7) wait_vmcnt<4>();
        else             wait_vmcnt<12>();
        comp_ht(2*p + 1, acc);
        if (p < 7) issue_ht(2*p + 3);

        // store: D col=c -> (site n0+p*4+sl, batch b0+bb); o = t*16+q*4+r
        const int n = n0 + p*4 + sl;
        float* op = out + ((size_t)(b0 + bb) * N_SITES + n) * OUT_DIM + q*4;
        #pragma unroll
        for (int t = 0; t < 4; ++t)
            *(f32x4*)(op + t*16) = acc[t] + bias_r[t];
    }
}

extern "C" void kernel_launch(void* const* d_in, const int* in_sizes, int n_in,
                              void* d_out, int out_size, void* d_ws, size_t ws_size,
                              hipStream_t stream) {
    const float* x       = (const float*)d_in[0];
    const float* W       = (const float*)d_in[1];
    const float* bias    = (const float*)d_in[2];
    const int*   kernel2 = (const int*)d_in[3];
    float* out = (float*)d_out;

    // 128 site-groups x 16 batch-groups = 2048 single-wave blocks (8/CU)
    conv_async_kernel<<<2048, 64, 0, stream>>>(x, W, bias, kernel2, out);
}

// Round 4
// 148.026 us; speedup vs baseline: 1.0122x; 1.0122x over previous
//
#include <hip/hip_runtime.h>
#include <stdint.h>

// conv_59700045414486: y[b,n,o] = sum_{k,c} x[b, kernel2[n,k], c] * W[k,c,o] + bias[o]
// B=64, N=4096, C=64, OUT=64, K2=4
//
// R9: R8 post-mortem — halving LDS + doubling grid (caps allow 8 blocks/CU)
// left OccupancyPercent EXACTLY at ~9% (~3 waves/CU) and perf unchanged.
// Per-wave resources are NOT the residency limiter; the evidence points at a
// concurrent-WORKGROUP limit (~3 single-wave WGs/CU device-wide, both R5 and
// R8). Discriminating experiment: pack 4 independent pipeline waves into one
// 256-thread workgroup (waves of a WG become resident atomically):
//   - 512 WGs x 4 waves = same 2048 waves; 2 WGs/CU -> 8 waves/CU.
//   - each wave keeps a PRIVATE 16896B LDS slice (4x16896=67584B/WG, 2/CU
//     fits 160KB), private vmcnt ledger, NO __syncthreads anywhere.
//   - vbi = blockIdx.x*4 + wid reproduces R8's site/batch decomposition.
// Pipeline per wave is identical to R8: register-free global_load_lds DMA,
// 8KB half-tiles double-buffered, exact vmcnt counting (steady wait = 12),
// W in 128 VGPRs of A-fragments, MFMA 16x16x32 bf16.

#define N_SITES  4096
#define C_DIM    64
#define OUT_DIM  64

typedef __attribute__((ext_vector_type(8))) short bf16x8;
typedef __attribute__((ext_vector_type(4))) float f32x4;

__device__ __forceinline__ uint32_t pack2_bf16(float f0, float f1) {
    uint32_t u0 = __float_as_uint(f0) + 0x8000u;
    uint32_t u1 = __float_as_uint(f1) + 0x8000u;
    return __builtin_amdgcn_perm(u1, u0, 0x07060302u);  // [bf16(f1)|bf16(f0)]
}

template<int N> __device__ __forceinline__ void wait_vmcnt() {
    asm volatile("s_waitcnt vmcnt(%0)" :: "n"(N) : "memory");
}

// async 16B/lane global->LDS DMA; LDS dst = M0 + lane*16 (wave-uniform M0)
__device__ __forceinline__ void gll16(const float* p, uint32_t m0v) {
    asm volatile("s_mov_b32 m0, %1\n\t"
                 "global_load_lds_dwordx4 %0, off"
                 :: "v"(p), "s"(m0v) : "memory");
}

__global__ __launch_bounds__(256, 1)
void conv_async_kernel(const float* __restrict__ x, const float* __restrict__ W,
                       const float* __restrict__ bias, const int* __restrict__ kernel2,
                       float* __restrict__ out)
{
    // per wave: [0,16384) two 8KB half-tile slots; [16384,16896) 32 int4 idx
    __shared__ __align__(1024) uint8_t lds_raw[4 * 16896];

    const int tid  = threadIdx.x;
    const int lane = tid & 63;
    const int wid  = tid >> 6;             // 4 independent pipeline waves
    const int vbi  = blockIdx.x * 4 + wid; // virtual block id, = R8's bi
    const int sg   = vbi >> 4;             // 128 site-groups of 32 sites
    const int bg   = vbi & 15;             // 16 batch-groups of 4
    const int n0   = sg * 32;
    const int b0   = bg * 4;

    const int c  = lane & 15;              // MFMA col = (site sl, batch bb)
    const int q  = lane >> 4;              // k-quad; D row (o) = q*4+reg
    const int sl = c >> 2;
    const int bb = c & 3;

    uint8_t* lds_w = lds_raw + wid * 16896;   // this wave's private slice

    // ---- stage this wave's kernel2 slice into LDS (in-loop idx reads are
    //      ds_read/lgkmcnt, keeping the vmcnt queue = tiles+stores only)
    if (lane < 32) {
        int4 iv = ((const int4*)kernel2)[n0 + lane];
        *(int4*)(lds_w + 16384 + lane * 16) = iv;
    }

    // ---- A-fragments of W in registers, for the whole kernel (128 VGPRs)
    // A[m=c][k=q*8+j] for o = t*16+c, kk-block s: aw[t][s]; s = tap*2 + hs
    bf16x8 aw[4][8];
    #pragma unroll
    for (int t = 0; t < 4; ++t)
        #pragma unroll
        for (int s = 0; s < 8; ++s) {
            uint32_t* ap = (uint32_t*)&aw[t][s];
            #pragma unroll
            for (int u = 0; u < 4; ++u) {
                float f0 = W[(size_t)(s*32 + q*8 + 2*u    ) * OUT_DIM + t*16 + c];
                float f1 = W[(size_t)(s*32 + q*8 + 2*u + 1) * OUT_DIM + t*16 + c];
                ap[u] = pack2_bf16(f0, f1);
            }
        }

    f32x4 bias_r[4];
    #pragma unroll
    for (int t = 0; t < 4; ++t) bias_r[t] = *(const f32x4*)&bias[t*16 + q*4];

    // per-lane gather base: batch plane + this lane's 16B piece (pcq = q)
    const float* gx = x + (size_t)(b0 + bb) * (N_SITES * C_DIM) + q * 4;

    // LDS byte offset of this wave's slice for M0 (wave-uniform)
    const uint32_t lds0 =
        __builtin_amdgcn_readfirstlane((uint32_t)(uintptr_t)lds_w);

    // drain prologue loads: vmcnt queue must start empty for exact counting
    wait_vmcnt<0>();

    // half-tile i: phase pp=i>>1, taps {2h, 2h+1} with h=i&1, LDS slot i&1.
    // slot layout: instr j2 = kl*4+hs*2+j at slot*8192 + j2*1024; lane(q,c)
    // within instr block at q*256 + c*16. readback for s_local=kl*2+hs:
    // b128 at slot*8192 + s_local*2048 + q*512 + c*16 (+256).
    auto issue_ht = [&](int i) {
        const uint8_t* ib = lds_w + 16384 + (i >> 1) * 64 + (i & 1) * 8;
        int2 iv0 = *(const int2*)(ib);        // sites sl=0..3, taps {2h,2h+1}
        int2 iv1 = *(const int2*)(ib + 16);
        int2 iv2 = *(const int2*)(ib + 32);
        int2 iv3 = *(const int2*)(ib + 48);
        const uint32_t m0b = lds0 + (uint32_t)(i & 1) * 8192;
        #pragma unroll
        for (int kl = 0; kl < 2; ++kl) {
            const int e0 = kl ? iv0.y : iv0.x;
            const int e1 = kl ? iv1.y : iv1.x;
            const int e2 = kl ? iv2.y : iv2.x;
            const int e3 = kl ? iv3.y : iv3.x;
            const int nk = (sl & 2) ? ((sl & 1) ? e3 : e2)
                                    : ((sl & 1) ? e1 : e0);
            const float* row = gx + (size_t)(uint32_t)nk * C_DIM;
            gll16(row,      m0b + (uint32_t)(kl*4 + 0) * 1024);  // hs0 j0
            gll16(row + 16, m0b + (uint32_t)(kl*4 + 1) * 1024);  // hs0 j1
            gll16(row + 32, m0b + (uint32_t)(kl*4 + 2) * 1024);  // hs1 j0
            gll16(row + 48, m0b + (uint32_t)(kl*4 + 3) * 1024);  // hs1 j1
        }
    };

    // compute half-tile i (4 K=32 blocks), accumulate; aw s-index = 4h+s_local
    auto comp_ht = [&](int i, f32x4* acc) {
        const uint32_t tb = (uint32_t)(i & 1) * 8192;
        const int hb = (i & 1) * 4;
        #pragma unroll
        for (int s = 0; s < 4; ++s) {
            const uint8_t* pb = lds_w + tb + s*2048 + q*512 + c*16;
            f32x4 xa = *(const f32x4*)(pb);        // kk-local q*8+0..3
            f32x4 xb = *(const f32x4*)(pb + 256);  // kk-local q*8+4..7
            bf16x8 bf;
            uint32_t* bp = (uint32_t*)&bf;
            bp[0] = pack2_bf16(xa[0], xa[1]);
            bp[1] = pack2_bf16(xa[2], xa[3]);
            bp[2] = pack2_bf16(xb[0], xb[1]);
            bp[3] = pack2_bf16(xb[2], xb[3]);
            #pragma unroll
            for (int t = 0; t < 4; ++t)
                acc[t] = __builtin_amdgcn_mfma_f32_16x16x32_bf16(aw[t][hb + s], bf, acc[t], 0, 0, 0);
        }
    };

    issue_ht(0);
    issue_ht(1);

    // 8 phases x 2 half-tiles. vmcnt accounting (younger-than-target):
    //  subA p=0: HT1 = 8;  subA p>=1: HT(2p+1) + S(p-1) = 12
    //  subB p=0: HT2 = 8;  subB 1<=p<=6: S(p-1) + HT(2p+2) = 12; p=7: S6 = 4
    #pragma unroll
    for (int p = 0; p < 8; ++p) {
        f32x4 acc[4];
        #pragma unroll
        for (int t = 0; t < 4; ++t) acc[t] = (f32x4){0.f, 0.f, 0.f, 0.f};

        if (p == 0) wait_vmcnt<8>();
        else        wait_vmcnt<12>();
        comp_ht(2*p, acc);
        if (p < 7) issue_ht(2*p + 2);

        if      (p == 0) wait_vmcnt<8>();
        else if (p == 7) wait_vmcnt<4>();
        else             wait_vmcnt<12>();
        comp_ht(2*p + 1, acc);
        if (p < 7) issue_ht(2*p + 3);

        // store: D col=c -> (site n0+p*4+sl, batch b0+bb); o = t*16+q*4+r
        const int n = n0 + p*4 + sl;
        float* op = out + ((size_t)(b0 + bb) * N_SITES + n) * OUT_DIM + q*4;
        #pragma unroll
        for (int t = 0; t < 4; ++t)
            *(f32x4*)(op + t*16) = acc[t] + bias_r[t];
    }
}

extern "C" void kernel_launch(void* const* d_in, const int* in_sizes, int n_in,
                              void* d_out, int out_size, void* d_ws, size_t ws_size,
                              hipStream_t stream) {
    const float* x       = (const float*)d_in[0];
    const float* W       = (const float*)d_in[1];
    const float* bias    = (const float*)d_in[2];
    const int*   kernel2 = (const int*)d_in[3];
    float* out = (float*)d_out;

    // 512 WGs x 4 waves = 2048 pipeline waves; 2 WGs/CU -> 8 waves/CU
    conv_async_kernel<<<512, 256, 0, stream>>>(x, W, bias, kernel2, out);
}

// Round 5
// 147.073 us; speedup vs baseline: 1.0188x; 1.0065x over previous
//
#include <hip/hip_runtime.h>
#include <stdint.h>

// conv_59700045414486: y[b,n,o] = sum_{k,c} x[b, kernel2[n,k], c] * W[k,c,o] + bias[o]
// B=64, N=4096, C=64, OUT=64, K2=4
//
// R10: post-mortem of R5/R8/R9 — wave count and queue depth both varied 2x
// with no perf change; R9's 4-wave WG regressed with FETCH +26% (locality
// signature). Two fixes, independently revertible:
//  (a) L2 batch-plane pinning: bi = half*1024 + sg*8 + bgl, bg = bgl+8*half.
//      XCD = bi%8 = bgl, so each XCD serves ONE batch-group (4 x-planes =
//      4MB = its L2) per temporal half. Gather reuse (4x) served from L2;
//      x fetched from HBM ~once (FETCH 85.6 -> ~68MB predicted).
//  (b) 4 LDS half-tile slots (was 2): prefetch distance 3 HTs, steady wait
//      vmcnt(32); per-HT stall = max(0, latency - 3*compute) instead of
//      (latency - 1*compute). LDS 33.3KB -> 4 blocks/CU (measured residency).
// Pipeline core unchanged from R8 (proven): register-free global_load_lds
// DMA, exact per-wave vmcnt ledger, W in 128 VGPRs, MFMA 16x16x32 bf16.

#define N_SITES  4096
#define C_DIM    64
#define OUT_DIM  64

typedef __attribute__((ext_vector_type(8))) short bf16x8;
typedef __attribute__((ext_vector_type(4))) float f32x4;

__device__ __forceinline__ uint32_t pack2_bf16(float f0, float f1) {
    uint32_t u0 = __float_as_uint(f0) + 0x8000u;
    uint32_t u1 = __float_as_uint(f1) + 0x8000u;
    return __builtin_amdgcn_perm(u1, u0, 0x07060302u);  // [bf16(f1)|bf16(f0)]
}

template<int N> __device__ __forceinline__ void wait_vmcnt() {
    asm volatile("s_waitcnt vmcnt(%0)" :: "n"(N) : "memory");
}

// async 16B/lane global->LDS DMA; LDS dst = M0 + lane*16 (wave-uniform M0)
__device__ __forceinline__ void gll16(const float* p, uint32_t m0v) {
    asm volatile("s_mov_b32 m0, %1\n\t"
                 "global_load_lds_dwordx4 %0, off"
                 :: "v"(p), "s"(m0v) : "memory");
}

__global__ __launch_bounds__(64, 1)
void conv_async_kernel(const float* __restrict__ x, const float* __restrict__ W,
                       const float* __restrict__ bias, const int* __restrict__ kernel2,
                       float* __restrict__ out)
{
    // [0,32768): four 8KB half-tile slots; [32768,33280): 32 sites' idx (int4)
    __shared__ __align__(1024) uint8_t lds_raw[33280];

    const int lane = threadIdx.x;          // 64 threads = 1 wave
    const int bi   = blockIdx.x;
    // (a) locality ordering: XCD (=bi%8) <-> batch-group, two temporal halves
    const int half = bi >> 10;             // 0: bg 0-7, 1: bg 8-15
    const int r    = bi & 1023;
    const int bgl  = r & 7;                // XCD binding = bi%8
    const int sg   = r >> 3;               // 128 site-groups of 32 sites
    const int bg   = bgl + half * 8;
    const int n0   = sg * 32;
    const int b0   = bg * 4;

    const int c  = lane & 15;              // MFMA col = (site sl, batch bb)
    const int q  = lane >> 4;              // k-quad; D row (o) = q*4+reg
    const int sl = c >> 2;
    const int bb = c & 3;

    // ---- stage this block's kernel2 slice into LDS (in-loop idx reads are
    //      ds_read/lgkmcnt, keeping the vmcnt queue = tiles+stores only)
    if (lane < 32) {
        int4 iv = ((const int4*)kernel2)[n0 + lane];
        *(int4*)(lds_raw + 32768 + lane * 16) = iv;
    }

    // ---- A-fragments of W in registers, for the whole kernel (128 VGPRs)
    // A[m=c][k=q*8+j] for o = t*16+c, kk-block s: aw[t][s]; s = tap*2 + hs
    bf16x8 aw[4][8];
    #pragma unroll
    for (int t = 0; t < 4; ++t)
        #pragma unroll
        for (int s = 0; s < 8; ++s) {
            uint32_t* ap = (uint32_t*)&aw[t][s];
            #pragma unroll
            for (int u = 0; u < 4; ++u) {
                float f0 = W[(size_t)(s*32 + q*8 + 2*u    ) * OUT_DIM + t*16 + c];
                float f1 = W[(size_t)(s*32 + q*8 + 2*u + 1) * OUT_DIM + t*16 + c];
                ap[u] = pack2_bf16(f0, f1);
            }
        }

    f32x4 bias_r[4];
    #pragma unroll
    for (int t = 0; t < 4; ++t) bias_r[t] = *(const f32x4*)&bias[t*16 + q*4];

    // per-lane gather base: batch plane + this lane's 16B piece (pcq = q)
    const float* gx = x + (size_t)(b0 + bb) * (N_SITES * C_DIM) + q * 4;

    // LDS byte offset of lds_raw for M0 (flat shared ptr low bits = offset)
    const uint32_t lds0 =
        __builtin_amdgcn_readfirstlane((uint32_t)(uintptr_t)lds_raw);

    // drain prologue loads: vmcnt queue must start empty for exact counting
    wait_vmcnt<0>();

    // half-tile i: phase i>>1, taps {2h,2h+1} with h=i&1, LDS slot i&3.
    // slot layout: instr j2 = kl*4+hs*2+j at slot*8192 + j2*1024; lane(q,c)
    // within instr block at q*256 + c*16. readback for s_local=kl*2+hs:
    // b128 at slot*8192 + s_local*2048 + q*512 + c*16 (+256).
    auto issue_ht = [&](int i) {
        const uint8_t* ib = lds_raw + 32768 + (i >> 1) * 64 + (i & 1) * 8;
        int2 iv0 = *(const int2*)(ib);        // sites sl=0..3, taps {2h,2h+1}
        int2 iv1 = *(const int2*)(ib + 16);
        int2 iv2 = *(const int2*)(ib + 32);
        int2 iv3 = *(const int2*)(ib + 48);
        const uint32_t m0b = lds0 + (uint32_t)(i & 3) * 8192;
        #pragma unroll
        for (int kl = 0; kl < 2; ++kl) {
            const int e0 = kl ? iv0.y : iv0.x;
            const int e1 = kl ? iv1.y : iv1.x;
            const int e2 = kl ? iv2.y : iv2.x;
            const int e3 = kl ? iv3.y : iv3.x;
            const int nk = (sl & 2) ? ((sl & 1) ? e3 : e2)
                                    : ((sl & 1) ? e1 : e0);
            const float* row = gx + (size_t)(uint32_t)nk * C_DIM;
            gll16(row,      m0b + (uint32_t)(kl*4 + 0) * 1024);  // hs0 j0
            gll16(row + 16, m0b + (uint32_t)(kl*4 + 1) * 1024);  // hs0 j1
            gll16(row + 32, m0b + (uint32_t)(kl*4 + 2) * 1024);  // hs1 j0
            gll16(row + 48, m0b + (uint32_t)(kl*4 + 3) * 1024);  // hs1 j1
        }
    };

    // compute half-tile i (4 K=32 blocks), accumulate; aw s-index = 4h+s_local
    auto comp_ht = [&](int i, f32x4* acc) {
        const uint32_t tb = (uint32_t)(i & 3) * 8192;
        const int hb = (i & 1) * 4;
        #pragma unroll
        for (int s = 0; s < 4; ++s) {
            const uint8_t* pb = lds_raw + tb + s*2048 + q*512 + c*16;
            f32x4 xa = *(const f32x4*)(pb);        // kk-local q*8+0..3
            f32x4 xb = *(const f32x4*)(pb + 256);  // kk-local q*8+4..7
            bf16x8 bf;
            uint32_t* bp = (uint32_t*)&bf;
            bp[0] = pack2_bf16(xa[0], xa[1]);
            bp[1] = pack2_bf16(xa[2], xa[3]);
            bp[2] = pack2_bf16(xb[0], xb[1]);
            bp[3] = pack2_bf16(xb[2], xb[3]);
            #pragma unroll
            for (int t = 0; t < 4; ++t)
                acc[t] = __builtin_amdgcn_mfma_f32_16x16x32_bf16(aw[t][hb + s], bf, acc[t], 0, 0, 0);
        }
    };

    issue_ht(0);
    issue_ht(1);
    issue_ht(2);
    issue_ht(3);

    // 8 phases x 2 half-tiles, prefetch distance 3 HTs (HT=8 ops, S=4 ops).
    // Issue order: H0..H3 | p: wA cA(H2p) [p<=5: iss H(2p+4)] wB cB(H2p+1)
    // [p<=5: iss H(2p+5)] S(p).  Younger-than-target ledger:
    //  wA: p0: H1..3=24; p1: H3,H4,H5,S0=28; p2..6: H+S+H+H+S=32; p7: H15,S5,S6=16
    //  wB: p0: H2,H3,H4=24; p1: H4,H5,S0,H6=28; p2..5: 32; p6: S4,H14,H15,S5=24; p7: S5,S6=8
    #pragma unroll
    for (int p = 0; p < 8; ++p) {
        f32x4 acc[4];
        #pragma unroll
        for (int t = 0; t < 4; ++t) acc[t] = (f32x4){0.f, 0.f, 0.f, 0.f};

        if      (p == 0) wait_vmcnt<24>();
        else if (p == 1) wait_vmcnt<28>();
        else if (p == 7) wait_vmcnt<16>();
        else             wait_vmcnt<32>();
        comp_ht(2*p, acc);
        if (p <= 5) issue_ht(2*p + 4);

        if      (p == 0) wait_vmcnt<24>();
        else if (p == 1) wait_vmcnt<28>();
        else if (p == 6) wait_vmcnt<24>();
        else if (p == 7) wait_vmcnt<8>();
        else             wait_vmcnt<32>();
        comp_ht(2*p + 1, acc);
        if (p <= 5) issue_ht(2*p + 5);

        // store: D col=c -> (site n0+p*4+sl, batch b0+bb); o = t*16+q*4+r
        const int n = n0 + p*4 + sl;
        float* op = out + ((size_t)(b0 + bb) * N_SITES + n) * OUT_DIM + q*4;
        #pragma unroll
        for (int t = 0; t < 4; ++t)
            *(f32x4*)(op + t*16) = acc[t] + bias_r[t];
    }
}

extern "C" void kernel_launch(void* const* d_in, const int* in_sizes, int n_in,
                              void* d_out, int out_size, void* d_ws, size_t ws_size,
                              hipStream_t stream) {
    const float* x       = (const float*)d_in[0];
    const float* W       = (const float*)d_in[1];
    const float* bias    = (const float*)d_in[2];
    const int*   kernel2 = (const int*)d_in[3];
    float* out = (float*)d_out;

    // 2048 single-wave blocks; two temporal halves of 1024 (= 4/CU, full
    // device generation); XCD k <- batch-group bgl=k within each half.
    conv_async_kernel<<<2048, 64, 0, stream>>>(x, W, bias, kernel2, out);
}

// Round 6
// 136.987 us; speedup vs baseline: 1.0938x; 1.0736x over previous
//
#include <hip/hip_runtime.h>
#include <stdint.h>

// conv_59700045414486: y[b,n,o] = sum_{k,c} x[b, kernel2[n,k], c] * W[k,c,o] + bias[o]
// B=64, N=4096, C=64, OUT=64, K2=4
//
// R11: R10 post-mortem — L2 pinning worked (FETCH 85.6->50MB) but time pinned
// at ~57us: gather SERVICE RATE is the wall (~133 cy per global_load_lds).
// Cause: per instruction, each 16-lane quarter-wave read 16 scattered 64B
// pieces (worst-case TA divergence, half-used 128B lines). Fix: remap DMA so
// each quarter-wave reads ONE contiguous 256B x-row (4 rows/instr: same
// site&tap, 4 batch planes). Same 8 instr/half-tile -> R10's vmcnt ledger,
// 4-slot pipeline, and locality ordering carry over unchanged.
//   - LDS tile row-major [tap kl][col c'=site*4+batch][256B row]; 32B chunks
//     within each row XOR-swizzled by (c'&3)=batch to break the 8-way read
//     bank conflict -> 2-way (free). Swizzle applied on the DMA SOURCE
//     address (dst of global_load_lds must stay linear); mask = lane>>4 is
//     instruction-independent -> folds into the per-lane base pointer gxn.
//   - readback: lane(q,c) reads 32B at chunk (hs*4+q)^(c&3) of row (kl,c).

#define N_SITES  4096
#define C_DIM    64
#define OUT_DIM  64

typedef __attribute__((ext_vector_type(8))) short bf16x8;
typedef __attribute__((ext_vector_type(4))) float f32x4;

__device__ __forceinline__ uint32_t pack2_bf16(float f0, float f1) {
    uint32_t u0 = __float_as_uint(f0) + 0x8000u;
    uint32_t u1 = __float_as_uint(f1) + 0x8000u;
    return __builtin_amdgcn_perm(u1, u0, 0x07060302u);  // [bf16(f1)|bf16(f0)]
}

template<int N> __device__ __forceinline__ void wait_vmcnt() {
    asm volatile("s_waitcnt vmcnt(%0)" :: "n"(N) : "memory");
}

// async 16B/lane global->LDS DMA; LDS dst = M0 + lane*16 (wave-uniform M0)
__device__ __forceinline__ void gll16(const float* p, uint32_t m0v) {
    asm volatile("s_mov_b32 m0, %1\n\t"
                 "global_load_lds_dwordx4 %0, off"
                 :: "v"(p), "s"(m0v) : "memory");
}

__global__ __launch_bounds__(64, 1)
void conv_async_kernel(const float* __restrict__ x, const float* __restrict__ W,
                       const float* __restrict__ bias, const int* __restrict__ kernel2,
                       float* __restrict__ out)
{
    // [0,32768): four 8KB half-tile slots; [32768,33280): 32 sites' idx (int4)
    __shared__ __align__(1024) uint8_t lds_raw[33280];

    const int lane = threadIdx.x;          // 64 threads = 1 wave
    const int bi   = blockIdx.x;
    // R10 locality ordering: XCD (=bi%8) <-> batch-group, two temporal halves
    const int half = bi >> 10;             // 0: bg 0-7, 1: bg 8-15
    const int r    = bi & 1023;
    const int bgl  = r & 7;                // XCD binding = bi%8
    const int sg   = r >> 3;               // 128 site-groups of 32 sites
    const int bg   = bgl + half * 8;
    const int n0   = sg * 32;
    const int b0   = bg * 4;

    const int c  = lane & 15;              // MFMA col = (site sl, batch bb)
    const int q  = lane >> 4;              // k-quad; D row (o) = q*4+reg
    const int sl = c >> 2;
    const int bb = c & 3;

    // DMA lane roles: quarter-wave g reads one row (batch b0+g); u = 16B unit
    const int g  = lane >> 4;
    const int u  = lane & 15;

    // ---- stage this block's kernel2 slice into LDS (in-loop idx reads are
    //      ds_read/lgkmcnt, keeping the vmcnt queue = tiles+stores only)
    if (lane < 32) {
        int4 iv = ((const int4*)kernel2)[n0 + lane];
        *(int4*)(lds_raw + 32768 + lane * 16) = iv;
    }

    // ---- A-fragments of W in registers, for the whole kernel (128 VGPRs)
    // A[m=c][k=q*8+j] for o = t*16+c, kk-block s: aw[t][s]; s = tap*2 + hs
    bf16x8 aw[4][8];
    #pragma unroll
    for (int t = 0; t < 4; ++t)
        #pragma unroll
        for (int s = 0; s < 8; ++s) {
            uint32_t* ap = (uint32_t*)&aw[t][s];
            #pragma unroll
            for (int uu = 0; uu < 4; ++uu) {
                float f0 = W[(size_t)(s*32 + q*8 + 2*uu    ) * OUT_DIM + t*16 + c];
                float f1 = W[(size_t)(s*32 + q*8 + 2*uu + 1) * OUT_DIM + t*16 + c];
                ap[uu] = pack2_bf16(f0, f1);
            }
        }

    f32x4 bias_r[4];
    #pragma unroll
    for (int t = 0; t < 4; ++t) bias_r[t] = *(const f32x4*)&bias[t*16 + q*4];

    // per-lane gather base: batch plane (b0+g) + source-swizzled within-row
    // offset: LDS 32B pos p=u>>1 receives global chunk p^g; +16B half (u&1).
    const float* gxn = x + (size_t)(b0 + g) * (N_SITES * C_DIM)
                     + (size_t)((((u >> 1) ^ g) * 8) + (u & 1) * 4);

    // LDS byte offset of lds_raw for M0 (flat shared ptr low bits = offset)
    const uint32_t lds0 =
        __builtin_amdgcn_readfirstlane((uint32_t)(uintptr_t)lds_raw);

    // drain prologue loads: vmcnt queue must start empty for exact counting
    wait_vmcnt<0>();

    // half-tile i: phase pp=i>>1, taps {2h,2h+1} (h=i&1), LDS slot i&3.
    // slot layout: tap kl at +kl*4096; col c'=sl'*4+batch at +c'*256;
    // row is 256B with 32B chunks permuted by ^batch (source-swizzled).
    // instr (kl,sl'): M0 = slot + kl*4096 + sl'*1024; quarter-wave g writes
    // col sl'*4+g. nk is wave-uniform (scalar idx from LDS).
    auto issue_ht = [&](int i) {
        const int pp = i >> 1, h = i & 1;
        const int* ibase = (const int*)(lds_raw + 32768 + pp * 64);
        const uint32_t m0s = lds0 + (uint32_t)(i & 3) * 8192;
        #pragma unroll
        for (int kl = 0; kl < 2; ++kl) {
            #pragma unroll
            for (int slp = 0; slp < 4; ++slp) {
                const int nk = ibase[slp * 4 + 2 * h + kl];
                const float* row = gxn + (size_t)(uint32_t)nk * C_DIM;
                gll16(row, m0s + (uint32_t)kl * 4096 + (uint32_t)slp * 1024);
            }
        }
    };

    // compute half-tile i (4 K=32 chunks), accumulate; aw s-index = 4h+kl*2+hs
    auto comp_ht = [&](int i, f32x4* acc) {
        const uint32_t tb = (uint32_t)(i & 3) * 8192;
        const int hb = (i & 1) * 4;
        #pragma unroll
        for (int kl = 0; kl < 2; ++kl)
        #pragma unroll
        for (int hs = 0; hs < 2; ++hs) {
            const uint8_t* pb = lds_raw + tb + (uint32_t)kl * 4096
                              + (uint32_t)c * 256
                              + (uint32_t)((((hs * 4 + q) ^ (c & 3)) * 32));
            f32x4 xa = *(const f32x4*)(pb);        // kk-local q*8+0..3
            f32x4 xb = *(const f32x4*)(pb + 16);   // kk-local q*8+4..7
            bf16x8 bf;
            uint32_t* bp = (uint32_t*)&bf;
            bp[0] = pack2_bf16(xa[0], xa[1]);
            bp[1] = pack2_bf16(xa[2], xa[3]);
            bp[2] = pack2_bf16(xb[0], xb[1]);
            bp[3] = pack2_bf16(xb[2], xb[3]);
            #pragma unroll
            for (int t = 0; t < 4; ++t)
                acc[t] = __builtin_amdgcn_mfma_f32_16x16x32_bf16(
                    aw[t][hb + kl * 2 + hs], bf, acc[t], 0, 0, 0);
        }
    };

    issue_ht(0);
    issue_ht(1);
    issue_ht(2);
    issue_ht(3);

    // 8 phases x 2 half-tiles, prefetch distance 3 HTs (HT=8 ops, S=4 ops).
    // Issue order: H0..H3 | p: wA cA(H2p) [p<=5: iss H(2p+4)] wB cB(H2p+1)
    // [p<=5: iss H(2p+5)] S(p).  Younger-than-target ledger (same as R10):
    //  wA: p0: H1..3=24; p1: H3,H4,H5,S0=28; p2..6: 32; p7: H15,S5,S6=16
    //  wB: p0: H2,H3,H4=24; p1: H4,H5,S0,H6=28; p2..5: 32; p6: 24; p7: 8
    #pragma unroll
    for (int p = 0; p < 8; ++p) {
        f32x4 acc[4];
        #pragma unroll
        for (int t = 0; t < 4; ++t) acc[t] = (f32x4){0.f, 0.f, 0.f, 0.f};

        if      (p == 0) wait_vmcnt<24>();
        else if (p == 1) wait_vmcnt<28>();
        else if (p == 7) wait_vmcnt<16>();
        else             wait_vmcnt<32>();
        comp_ht(2*p, acc);
        if (p <= 5) issue_ht(2*p + 4);

        if      (p == 0) wait_vmcnt<24>();
        else if (p == 1) wait_vmcnt<28>();
        else if (p == 6) wait_vmcnt<24>();
        else if (p == 7) wait_vmcnt<8>();
        else             wait_vmcnt<32>();
        comp_ht(2*p + 1, acc);
        if (p <= 5) issue_ht(2*p + 5);

        // store: D col=c -> (site n0+p*4+sl, batch b0+bb); o = t*16+q*4+r
        const int n = n0 + p*4 + sl;
        float* op = out + ((size_t)(b0 + bb) * N_SITES + n) * OUT_DIM + q*4;
        #pragma unroll
        for (int t = 0; t < 4; ++t)
            *(f32x4*)(op + t*16) = acc[t] + bias_r[t];
    }
}

extern "C" void kernel_launch(void* const* d_in, const int* in_sizes, int n_in,
                              void* d_out, int out_size, void* d_ws, size_t ws_size,
                              hipStream_t stream) {
    const float* x       = (const float*)d_in[0];
    const float* W       = (const float*)d_in[1];
    const float* bias    = (const float*)d_in[2];
    const int*   kernel2 = (const int*)d_in[3];
    float* out = (float*)d_out;

    // 2048 single-wave blocks; two temporal halves of 1024 (= 4/CU, full
    // device generation); XCD k <- batch-group bgl=k within each half.
    conv_async_kernel<<<2048, 64, 0, stream>>>(x, W, bias, kernel2, out);
}